// Round 9
// baseline (705.238 us; speedup 1.0000x reference)
//
#include <hip/hip_runtime.h>
#include <hip/hip_bf16.h>
#include <math.h>

#define N 512
#define DIM 64

typedef __attribute__((ext_vector_type(8))) short short8;
typedef __attribute__((ext_vector_type(4))) float f32x4;

// workspace layout (units: floats from base)
#define WS_Q 0
#define WS_K (N*DIM)
#define WS_V (2*N*DIM)
#define WS_A (3*N*DIM)
#define WS_B (4*N*DIM)
#define WS_ATT (5*N*DIM)
#define WS_MEAN (6*N*DIM)
#define WS_MAXK (6*N*DIM + DIM)   // uint keys

__device__ __forceinline__ unsigned short f2bf(float f) {
    unsigned u = __float_as_uint(f);
    return (unsigned short)((u + 0x7fffu + ((u >> 16) & 1u)) >> 16);
}

// ------------------------------------------------- qkv + A/B precompute
__global__ void k_qkv(const float* __restrict__ feat, const float* __restrict__ Wqkv,
                      const float* __restrict__ bqkv, const float* __restrict__ Wg1,
                      const float* __restrict__ bg1, float* __restrict__ ws) {
    __shared__ float frow[DIM];
    __shared__ float qrow[DIM];
    __shared__ float krow[DIM];
    int i = blockIdx.x;
    int c = threadIdx.x;              // 0..191
    if (i == 0 && c < DIM) {
        ws[WS_MEAN + c] = 0.0f;
        ((unsigned*)ws)[WS_MAXK + c] = 0u;
    }
    if (c < DIM) frow[c] = feat[i * DIM + c];
    __syncthreads();
    float a0 = bqkv[c], a1 = 0.f, a2 = 0.f, a3 = 0.f;
#pragma unroll
    for (int kk = 0; kk < DIM; kk += 4) {
        a0 += frow[kk + 0] * Wqkv[(kk + 0) * 3 * DIM + c];
        a1 += frow[kk + 1] * Wqkv[(kk + 1) * 3 * DIM + c];
        a2 += frow[kk + 2] * Wqkv[(kk + 2) * 3 * DIM + c];
        a3 += frow[kk + 3] * Wqkv[(kk + 3) * 3 * DIM + c];
    }
    float acc = (a0 + a1) + (a2 + a3);
    if (c < DIM) {
        ws[WS_Q + i * DIM + c] = acc;
        qrow[c] = acc;
    } else if (c < 2 * DIM) {
        ws[WS_K + i * DIM + (c - DIM)] = acc;
        krow[c - DIM] = acc;
    } else {
        ws[WS_V + i * DIM + (c - 2 * DIM)] = acc;
    }
    __syncthreads();
    if (c < 2 * DIM) {
        const float* src = (c < DIM) ? qrow : krow;
        int cc = (c < DIM) ? c : c - DIM;
        float b0 = (c < DIM) ? bg1[c] : 0.0f, b1 = 0.f, b2 = 0.f, b3 = 0.f;
#pragma unroll
        for (int kk = 0; kk < DIM; kk += 4) {
            b0 += src[kk + 0] * Wg1[(kk + 0) * DIM + cc];
            b1 += src[kk + 1] * Wg1[(kk + 1) * DIM + cc];
            b2 += src[kk + 2] * Wg1[(kk + 2) * DIM + cc];
            b3 += src[kk + 3] * Wg1[(kk + 3) * DIM + cc];
        }
        float r = (b0 + b1) + (b2 + b3);
        if (c < DIM) ws[WS_A + i * DIM + c] = r;
        else         ws[WS_B + i * DIM + cc] = r;
    }
}

// ---------------------------------------------------------- fused attention
// one block per query row i; 4 waves x 256 threads; barrier-free main loop.
// VGPR budget <=128 (launch_bounds 256,4) -> 4 blocks/CU (LDS 38400 B x 4
// = 150 KB <= 160 KB), 16 waves/CU. Tables in LDS: (eq | ek*LOG2E) packed
// as 2xbf16 per u32, ev raw f32; row stride 65. MFMA epilogue, per-n state.
__global__ __launch_bounds__(256, 4) void k_attn(
    const float* __restrict__ dist,
    const float* __restrict__ tx, const float* __restrict__ ty,
    const float* __restrict__ tz, const float* __restrict__ Wg2,
    const float* __restrict__ bg2, float* __restrict__ ws) {
    __shared__ unsigned sxqk[24 * 65];
    __shared__ unsigned syqk[24 * 65];
    __shared__ unsigned szqk[16 * 65];
    __shared__ float sxv[24 * 65];
    __shared__ float syv[24 * 65];
    __shared__ float szv[16 * 65];
    __shared__ int sidx[N];
    __shared__ float smrg[4][4][16][3];   // [wave][n][l15][m,l,a]

    const int i = blockIdx.x;
    const int tid = threadIdx.x;
    const int w = tid >> 6;          // 0..3
    const int lane = tid & 63;
    const int l15 = lane & 15;
    const int kg = lane >> 4;
    const float LOG2E = 1.4426950408889634f;

    for (int t = tid; t < 24 * 64; t += 256) {
        int row = t >> 6, d = t & 63, o = row * 65 + d;
        sxqk[o] = (__float_as_uint(tx[t]) & 0xffff0000u) |
                  (__float_as_uint(tx[1536 + t] * LOG2E) >> 16);
        syqk[o] = (__float_as_uint(ty[t]) & 0xffff0000u) |
                  (__float_as_uint(ty[1536 + t] * LOG2E) >> 16);
        sxv[o] = tx[3072 + t];
        syv[o] = ty[3072 + t];
    }
    for (int t = tid; t < 16 * 64; t += 256) {
        int row = t >> 6, d = t & 63, o = row * 65 + d;
        szqk[o] = (__float_as_uint(tz[t]) & 0xffff0000u) |
                  (__float_as_uint(tz[1024 + t] * LOG2E) >> 16);
        szv[o] = tz[2048 + t];
    }
    for (int j = tid; j < N; j += 256) {
        const float* dp = dist + ((size_t)i * N + j) * 3;
        int ix = min((int)floorf((dp[0] + 3.0f) * 4.0f), 23);
        int iy = min((int)floorf((dp[1] + 3.0f) * 4.0f), 23);
        int iz = min((int)floorf((dp[2] + 2.0f) * 4.0f), 15);
        sidx[j] = ix | (iy << 5) | (iz << 10);
    }

    short8 wB[4][2];
#pragma unroll
    for (int n = 0; n < 4; ++n)
#pragma unroll
        for (int ks = 0; ks < 2; ++ks) {
            union { short8 v; unsigned short u[8]; } tmp;
#pragma unroll
            for (int e = 0; e < 8; ++e)
                tmp.u[e] = f2bf(Wg2[(ks * 32 + kg * 8 + e) * DIM + n * 16 + l15] * LOG2E);
            wB[n][ks] = tmp.v;
        }
    float af[2][8];
    {
        const float* ap = ws + WS_A + i * DIM + kg * 8;
#pragma unroll
        for (int ks = 0; ks < 2; ++ks)
#pragma unroll
            for (int e = 0; e < 8; ++e) af[ks][e] = ap[ks * 32 + e];
    }
    float qr[4], br[4];
#pragma unroll
    for (int n = 0; n < 4; ++n) {
        qr[n] = ws[WS_Q + i * DIM + n * 16 + l15] * LOG2E;
        br[n] = bg2[n * 16 + l15] * LOG2E;
    }

    const float* Bp = ws + WS_B;
    const float* Kp = ws + WS_K;
    const float* Vp = ws + WS_V;

    float stm[4], stl[4], sta[4];
#pragma unroll
    for (int n = 0; n < 4; ++n) { stm[n] = -INFINITY; stl[n] = 0.f; sta[n] = 0.f; }
    __syncthreads();

    // 32 slices of 16 j; wave w takes slices w, w+4, w+8, ..., w+28
#pragma unroll
    for (int t4 = 0; t4 < 8; ++t4) {
        const int j0w = (w + 4 * t4) * 16;
        short8 h[2];
        {
            const float* bb = Bp + (j0w + l15) * DIM + kg * 8;
#pragma unroll
            for (int ks = 0; ks < 2; ++ks) {
                union { short8 v; unsigned short u[8]; } hh;
#pragma unroll
                for (int e = 0; e < 8; ++e)
                    hh.u[e] = f2bf(fmaxf(af[ks][e] - bb[ks * 32 + e], 0.f));
                h[ks] = hh.v;
            }
        }
        f32x4 acc[4];
#pragma unroll
        for (int n = 0; n < 4; ++n) {
            acc[n] = (f32x4)(br[n]);   // fold bg2*LOG2E into C-init
            acc[n] = __builtin_amdgcn_mfma_f32_16x16x32_bf16(h[0], wB[n][0], acc[n], 0, 0, 0);
            acc[n] = __builtin_amdgcn_mfma_f32_16x16x32_bf16(h[1], wB[n][1], acc[n], 0, 0, 0);
        }
        int pk[4];
#pragma unroll
        for (int rr = 0; rr < 4; ++rr) pk[rr] = sidx[j0w + kg * 4 + rr];
#pragma unroll
        for (int n = 0; n < 4; ++n) {
            const int dof = n * 16 + l15;
            float rel2[4], vvv[4];
#pragma unroll
            for (int rr = 0; rr < 4; ++rr) {
                int ix = pk[rr] & 31, iy = (pk[rr] >> 5) & 31, iz = pk[rr] >> 10;
                unsigned ux = sxqk[ix * 65 + dof];
                unsigned uy = syqk[iy * 65 + dof];
                unsigned uz = szqk[iz * 65 + dof];
                float eq = __uint_as_float(ux & 0xffff0000u) +
                           __uint_as_float(uy & 0xffff0000u) +
                           __uint_as_float(uz & 0xffff0000u);
                float ek = __uint_as_float(ux << 16) +
                           __uint_as_float(uy << 16) +
                           __uint_as_float(uz << 16);      // LOG2E-scaled
                float ev = sxv[ix * 65 + dof] + syv[iy * 65 + dof] + szv[iz * 65 + dof];
                int j = j0w + kg * 4 + rr;
                float kv = Kp[j * DIM + dof];
                float vv = Vp[j * DIM + dof];
                rel2[rr] = acc[n][rr] + qr[n] * eq + kv * ek;  // log2-domain
                vvv[rr] = vv + ev;
            }
            float mx = fmaxf(fmaxf(rel2[0], rel2[1]), fmaxf(rel2[2], rel2[3]));
            float mn = fmaxf(stm[n], mx);
            float sc = exp2f(stm[n] - mn);
            float sl = 0.f, sa = 0.f;
#pragma unroll
            for (int rr = 0; rr < 4; ++rr) {
                float p = exp2f(rel2[rr] - mn);
                sl += p;
                sa = fmaf(p, vvv[rr], sa);
            }
            stl[n] = fmaf(stl[n], sc, sl);
            sta[n] = fmaf(sta[n], sc, sa);
            stm[n] = mn;
        }
    }

    // reduce over kg subgroups within wave (lanes kg=0..3 hold same d)
#pragma unroll
    for (int n = 0; n < 4; ++n) {
#pragma unroll
        for (int off = 16; off <= 32; off <<= 1) {
            float om = __shfl_xor(stm[n], off);
            float ol = __shfl_xor(stl[n], off);
            float oa = __shfl_xor(sta[n], off);
            float mn = fmaxf(stm[n], om);
            float s1 = exp2f(stm[n] - mn), s2 = exp2f(om - mn);
            stl[n] = stl[n] * s1 + ol * s2;
            sta[n] = sta[n] * s1 + oa * s2;
            stm[n] = mn;
        }
        if (lane < 16) {
            smrg[w][n][l15][0] = stm[n];
            smrg[w][n][l15][1] = stl[n];
            smrg[w][n][l15][2] = sta[n];
        }
    }
    __syncthreads();
    if (tid < DIM) {
        int n = tid >> 4, c = tid & 15;
        float m = smrg[0][n][c][0], l = smrg[0][n][c][1], a = smrg[0][n][c][2];
#pragma unroll
        for (int ww = 1; ww < 4; ++ww) {
            float om = smrg[ww][n][c][0], ol = smrg[ww][n][c][1], oa = smrg[ww][n][c][2];
            float mn = fmaxf(m, om);
            float s1 = exp2f(m - mn), s2 = exp2f(om - mn);
            l = l * s1 + ol * s2;
            a = a * s1 + oa * s2;
            m = mn;
        }
        float att = a / l;
        ws[WS_ATT + i * DIM + tid] = att;
        atomicAdd(ws + WS_MEAN + tid, att);
        unsigned u = __float_as_uint(att);
        unsigned key = (u & 0x80000000u) ? ~u : (u | 0x80000000u);
        atomicMax((unsigned*)ws + WS_MAXK + tid, key);
    }
}

// ------------------------------------------- final GEMM + LayerNorm + ReLU
__global__ void k_final(const float* __restrict__ ws, const float* __restrict__ Wd,
                        const float* __restrict__ bd, const float* __restrict__ lng,
                        const float* __restrict__ lnb, float* __restrict__ out) {
    __shared__ float xs[3 * DIM];
    __shared__ float hp[4][DIM];
    int i = blockIdx.x;
    int tid = threadIdx.x;            // 0..255
    int c = tid & 63, q = tid >> 6;
    if (tid < DIM) xs[tid] = ws[WS_ATT + i * DIM + tid];
    else if (tid < 2 * DIM) xs[tid] = ws[WS_MEAN + (tid - DIM)] * (1.0f / (float)N);
    else if (tid < 3 * DIM) {
        unsigned key = ((const unsigned*)ws)[WS_MAXK + (tid - 2 * DIM)];
        unsigned ub = (key & 0x80000000u) ? (key & 0x7fffffffu) : ~key;
        xs[tid] = __uint_as_float(ub);
    }
    __syncthreads();
    float p0 = (q == 0) ? bd[c] : 0.0f, p1 = 0.f;
#pragma unroll
    for (int kk = q * 48; kk < q * 48 + 48; kk += 2) {
        p0 += xs[kk] * Wd[kk * DIM + c];
        p1 += xs[kk + 1] * Wd[(kk + 1) * DIM + c];
    }
    hp[q][c] = p0 + p1;
    __syncthreads();
    if (tid < DIM) {
        float h = hp[0][tid] + hp[1][tid] + hp[2][tid] + hp[3][tid];
        float s = h;
#pragma unroll
        for (int off = 32; off >= 1; off >>= 1) s += __shfl_xor(s, off);
        float mu = s * (1.0f / DIM);
        float dif = h - mu;
        float s2 = dif * dif;
#pragma unroll
        for (int off = 32; off >= 1; off >>= 1) s2 += __shfl_xor(s2, off);
        float var = s2 * (1.0f / DIM);
        float rs = rsqrtf(var + 1e-5f);
        float o = dif * rs * lng[tid] + lnb[tid];
        out[i * DIM + tid] = fmaxf(o, 0.0f);
    }
}

// ---------------------------------------------------------------- launcher
extern "C" void kernel_launch(void* const* d_in, const int* in_sizes, int n_in,
                              void* d_out, int out_size, void* d_ws, size_t ws_size,
                              hipStream_t stream) {
    (void)in_sizes; (void)n_in; (void)out_size; (void)ws_size;
    const float* feat = (const float*)d_in[0];
    const float* dist = (const float*)d_in[1];
    const float* Wqkv = (const float*)d_in[2];
    const float* bqkv = (const float*)d_in[3];
    const float* Wg1  = (const float*)d_in[4];
    const float* bg1  = (const float*)d_in[5];
    const float* Wg2  = (const float*)d_in[6];
    const float* bg2  = (const float*)d_in[7];
    const float* tx   = (const float*)d_in[8];
    const float* ty   = (const float*)d_in[9];
    const float* tz   = (const float*)d_in[10];
    const float* Wd   = (const float*)d_in[11];
    const float* bd   = (const float*)d_in[12];
    const float* lng  = (const float*)d_in[13];
    const float* lnb  = (const float*)d_in[14];
    float* ws = (float*)d_ws;
    float* out = (float*)d_out;

    hipLaunchKernelGGL(k_qkv, dim3(N), dim3(192), 0, stream, feat, Wqkv, bqkv, Wg1, bg1, ws);
    hipLaunchKernelGGL(k_attn, dim3(N), dim3(256), 0, stream, dist, tx, ty, tz, Wg2, bg2, ws);
    hipLaunchKernelGGL(k_final, dim3(N), dim3(256), 0, stream, ws, Wd, bd, lng, lnb, out);
}

// Round 11
// 153.945 us; speedup vs baseline: 4.5811x; 4.5811x over previous
//
#include <hip/hip_runtime.h>
#include <hip/hip_bf16.h>
#include <math.h>

#define N 512
#define DIM 64

typedef __attribute__((ext_vector_type(8))) short short8;
typedef __attribute__((ext_vector_type(4))) float f32x4;

// workspace layout (units: floats from base)
#define WS_Q 0
#define WS_K (N*DIM)
#define WS_V (2*N*DIM)
#define WS_A (3*N*DIM)
#define WS_B (4*N*DIM)
#define WS_ATT (5*N*DIM)
#define WS_MEAN (6*N*DIM)
#define WS_MAXK (6*N*DIM + DIM)   // uint keys

__device__ __forceinline__ unsigned short f2bf(float f) {
    unsigned u = __float_as_uint(f);
    return (unsigned short)((u + 0x7fffu + ((u >> 16) & 1u)) >> 16);
}

// ------------------------------------------------- qkv + A/B precompute
__global__ void k_qkv(const float* __restrict__ feat, const float* __restrict__ Wqkv,
                      const float* __restrict__ bqkv, const float* __restrict__ Wg1,
                      const float* __restrict__ bg1, float* __restrict__ ws) {
    __shared__ float frow[DIM];
    __shared__ float qrow[DIM];
    __shared__ float krow[DIM];
    int i = blockIdx.x;
    int c = threadIdx.x;              // 0..191
    if (i == 0 && c < DIM) {
        ws[WS_MEAN + c] = 0.0f;
        ((unsigned*)ws)[WS_MAXK + c] = 0u;
    }
    if (c < DIM) frow[c] = feat[i * DIM + c];
    __syncthreads();
    float a0 = bqkv[c], a1 = 0.f, a2 = 0.f, a3 = 0.f;
#pragma unroll
    for (int kk = 0; kk < DIM; kk += 4) {
        a0 += frow[kk + 0] * Wqkv[(kk + 0) * 3 * DIM + c];
        a1 += frow[kk + 1] * Wqkv[(kk + 1) * 3 * DIM + c];
        a2 += frow[kk + 2] * Wqkv[(kk + 2) * 3 * DIM + c];
        a3 += frow[kk + 3] * Wqkv[(kk + 3) * 3 * DIM + c];
    }
    float acc = (a0 + a1) + (a2 + a3);
    if (c < DIM) {
        ws[WS_Q + i * DIM + c] = acc;
        qrow[c] = acc;
    } else if (c < 2 * DIM) {
        ws[WS_K + i * DIM + (c - DIM)] = acc;
        krow[c - DIM] = acc;
    } else {
        ws[WS_V + i * DIM + (c - 2 * DIM)] = acc;
    }
    __syncthreads();
    if (c < 2 * DIM) {
        const float* src = (c < DIM) ? qrow : krow;
        int cc = (c < DIM) ? c : c - DIM;
        float b0 = (c < DIM) ? bg1[c] : 0.0f, b1 = 0.f, b2 = 0.f, b3 = 0.f;
#pragma unroll
        for (int kk = 0; kk < DIM; kk += 4) {
            b0 += src[kk + 0] * Wg1[(kk + 0) * DIM + cc];
            b1 += src[kk + 1] * Wg1[(kk + 1) * DIM + cc];
            b2 += src[kk + 2] * Wg1[(kk + 2) * DIM + cc];
            b3 += src[kk + 3] * Wg1[(kk + 3) * DIM + cc];
        }
        float r = (b0 + b1) + (b2 + b3);
        if (c < DIM) ws[WS_A + i * DIM + c] = r;
        else         ws[WS_B + i * DIM + cc] = r;
    }
}

// ---------------------------------------------------------- fused attention
// one block per query row i; 4 waves x 256 threads; barrier-free main loop.
// launch_bounds (256,2): round-5-verified -> ~120 VGPR, NO spill; at 120
// VGPR occupancy is 4 waves/SIMD naturally; LDS 38400 B -> 4 blocks/CU.
// Tables in LDS: (eq | ek*LOG2E) packed as 2xbf16 per u32, ev raw f32;
// row stride 65. MFMA epilogue, per-n softmax state.
__global__ __launch_bounds__(256, 2) void k_attn(
    const float* __restrict__ dist,
    const float* __restrict__ tx, const float* __restrict__ ty,
    const float* __restrict__ tz, const float* __restrict__ Wg2,
    const float* __restrict__ bg2, float* __restrict__ ws) {
    __shared__ unsigned sxqk[24 * 65];
    __shared__ unsigned syqk[24 * 65];
    __shared__ unsigned szqk[16 * 65];
    __shared__ float sxv[24 * 65];
    __shared__ float syv[24 * 65];
    __shared__ float szv[16 * 65];
    __shared__ int sidx[N];
    __shared__ float smrg[4][4][16][3];   // [wave][n][l15][m,l,a]

    const int i = blockIdx.x;
    const int tid = threadIdx.x;
    const int w = tid >> 6;          // 0..3
    const int lane = tid & 63;
    const int l15 = lane & 15;
    const int kg = lane >> 4;
    const float LOG2E = 1.4426950408889634f;

    for (int t = tid; t < 24 * 64; t += 256) {
        int row = t >> 6, d = t & 63, o = row * 65 + d;
        sxqk[o] = (__float_as_uint(tx[t]) & 0xffff0000u) |
                  (__float_as_uint(tx[1536 + t] * LOG2E) >> 16);
        syqk[o] = (__float_as_uint(ty[t]) & 0xffff0000u) |
                  (__float_as_uint(ty[1536 + t] * LOG2E) >> 16);
        sxv[o] = tx[3072 + t];
        syv[o] = ty[3072 + t];
    }
    for (int t = tid; t < 16 * 64; t += 256) {
        int row = t >> 6, d = t & 63, o = row * 65 + d;
        szqk[o] = (__float_as_uint(tz[t]) & 0xffff0000u) |
                  (__float_as_uint(tz[1024 + t] * LOG2E) >> 16);
        szv[o] = tz[2048 + t];
    }
    for (int j = tid; j < N; j += 256) {
        const float* dp = dist + ((size_t)i * N + j) * 3;
        int ix = min((int)floorf((dp[0] + 3.0f) * 4.0f), 23);
        int iy = min((int)floorf((dp[1] + 3.0f) * 4.0f), 23);
        int iz = min((int)floorf((dp[2] + 2.0f) * 4.0f), 15);
        sidx[j] = ix | (iy << 5) | (iz << 10);
    }

    short8 wB[4][2];
#pragma unroll
    for (int n = 0; n < 4; ++n)
#pragma unroll
        for (int ks = 0; ks < 2; ++ks) {
            union { short8 v; unsigned short u[8]; } tmp;
#pragma unroll
            for (int e = 0; e < 8; ++e)
                tmp.u[e] = f2bf(Wg2[(ks * 32 + kg * 8 + e) * DIM + n * 16 + l15] * LOG2E);
            wB[n][ks] = tmp.v;
        }
    float af[2][8];
    {
        const float* ap = ws + WS_A + i * DIM + kg * 8;
#pragma unroll
        for (int ks = 0; ks < 2; ++ks)
#pragma unroll
            for (int e = 0; e < 8; ++e) af[ks][e] = ap[ks * 32 + e];
    }
    float qr[4], br[4];
#pragma unroll
    for (int n = 0; n < 4; ++n) {
        qr[n] = ws[WS_Q + i * DIM + n * 16 + l15] * LOG2E;
        br[n] = bg2[n * 16 + l15] * LOG2E;
    }

    const float* Bp = ws + WS_B;
    const float* Kp = ws + WS_K;
    const float* Vp = ws + WS_V;

    float stm[4], stl[4], sta[4];
#pragma unroll
    for (int n = 0; n < 4; ++n) { stm[n] = -INFINITY; stl[n] = 0.f; sta[n] = 0.f; }
    __syncthreads();

    // 32 slices of 16 j; wave w takes slices w, w+4, w+8, ..., w+28
#pragma unroll 2
    for (int t4 = 0; t4 < 8; ++t4) {
        const int j0w = (w + 4 * t4) * 16;
        short8 h[2];
        {
            const float* bb = Bp + (j0w + l15) * DIM + kg * 8;
#pragma unroll
            for (int ks = 0; ks < 2; ++ks) {
                union { short8 v; unsigned short u[8]; } hh;
#pragma unroll
                for (int e = 0; e < 8; ++e)
                    hh.u[e] = f2bf(fmaxf(af[ks][e] - bb[ks * 32 + e], 0.f));
                h[ks] = hh.v;
            }
        }
        f32x4 acc[4];
#pragma unroll
        for (int n = 0; n < 4; ++n) {
            acc[n] = (f32x4)(br[n]);   // fold bg2*LOG2E into C-init
            acc[n] = __builtin_amdgcn_mfma_f32_16x16x32_bf16(h[0], wB[n][0], acc[n], 0, 0, 0);
            acc[n] = __builtin_amdgcn_mfma_f32_16x16x32_bf16(h[1], wB[n][1], acc[n], 0, 0, 0);
        }
        int pk[4];
#pragma unroll
        for (int rr = 0; rr < 4; ++rr) pk[rr] = sidx[j0w + kg * 4 + rr];
#pragma unroll
        for (int n = 0; n < 4; ++n) {
            const int dof = n * 16 + l15;
            float rel2[4], vvv[4];
#pragma unroll
            for (int rr = 0; rr < 4; ++rr) {
                int ix = pk[rr] & 31, iy = (pk[rr] >> 5) & 31, iz = pk[rr] >> 10;
                unsigned ux = sxqk[ix * 65 + dof];
                unsigned uy = syqk[iy * 65 + dof];
                unsigned uz = szqk[iz * 65 + dof];
                float eq = __uint_as_float(ux & 0xffff0000u) +
                           __uint_as_float(uy & 0xffff0000u) +
                           __uint_as_float(uz & 0xffff0000u);
                float ek = __uint_as_float(ux << 16) +
                           __uint_as_float(uy << 16) +
                           __uint_as_float(uz << 16);      // LOG2E-scaled
                float ev = sxv[ix * 65 + dof] + syv[iy * 65 + dof] + szv[iz * 65 + dof];
                int j = j0w + kg * 4 + rr;
                float kv = Kp[j * DIM + dof];
                float vv = Vp[j * DIM + dof];
                rel2[rr] = acc[n][rr] + qr[n] * eq + kv * ek;  // log2-domain
                vvv[rr] = vv + ev;
            }
            float mx = fmaxf(fmaxf(rel2[0], rel2[1]), fmaxf(rel2[2], rel2[3]));
            float mn = fmaxf(stm[n], mx);
            float sc = exp2f(stm[n] - mn);
            float sl = 0.f, sa = 0.f;
#pragma unroll
            for (int rr = 0; rr < 4; ++rr) {
                float p = exp2f(rel2[rr] - mn);
                sl += p;
                sa = fmaf(p, vvv[rr], sa);
            }
            stl[n] = fmaf(stl[n], sc, sl);
            sta[n] = fmaf(sta[n], sc, sa);
            stm[n] = mn;
        }
    }

    // reduce over kg subgroups within wave (lanes kg=0..3 hold same d)
#pragma unroll
    for (int n = 0; n < 4; ++n) {
#pragma unroll
        for (int off = 16; off <= 32; off <<= 1) {
            float om = __shfl_xor(stm[n], off);
            float ol = __shfl_xor(stl[n], off);
            float oa = __shfl_xor(sta[n], off);
            float mn = fmaxf(stm[n], om);
            float s1 = exp2f(stm[n] - mn), s2 = exp2f(om - mn);
            stl[n] = stl[n] * s1 + ol * s2;
            sta[n] = sta[n] * s1 + oa * s2;
            stm[n] = mn;
        }
        if (lane < 16) {
            smrg[w][n][l15][0] = stm[n];
            smrg[w][n][l15][1] = stl[n];
            smrg[w][n][l15][2] = sta[n];
        }
    }
    __syncthreads();
    if (tid < DIM) {
        int n = tid >> 4, c = tid & 15;
        float m = smrg[0][n][c][0], l = smrg[0][n][c][1], a = smrg[0][n][c][2];
#pragma unroll
        for (int ww = 1; ww < 4; ++ww) {
            float om = smrg[ww][n][c][0], ol = smrg[ww][n][c][1], oa = smrg[ww][n][c][2];
            float mn = fmaxf(m, om);
            float s1 = exp2f(m - mn), s2 = exp2f(om - mn);
            l = l * s1 + ol * s2;
            a = a * s1 + oa * s2;
            m = mn;
        }
        float att = a / l;
        ws[WS_ATT + i * DIM + tid] = att;
        atomicAdd(ws + WS_MEAN + tid, att);
        unsigned u = __float_as_uint(att);
        unsigned key = (u & 0x80000000u) ? ~u : (u | 0x80000000u);
        atomicMax((unsigned*)ws + WS_MAXK + tid, key);
    }
}

// ------------------------------------------- final GEMM + LayerNorm + ReLU
__global__ void k_final(const float* __restrict__ ws, const float* __restrict__ Wd,
                        const float* __restrict__ bd, const float* __restrict__ lng,
                        const float* __restrict__ lnb, float* __restrict__ out) {
    __shared__ float xs[3 * DIM];
    __shared__ float hp[4][DIM];
    int i = blockIdx.x;
    int tid = threadIdx.x;            // 0..255
    int c = tid & 63, q = tid >> 6;
    if (tid < DIM) xs[tid] = ws[WS_ATT + i * DIM + tid];
    else if (tid < 2 * DIM) xs[tid] = ws[WS_MEAN + (tid - DIM)] * (1.0f / (float)N);
    else if (tid < 3 * DIM) {
        unsigned key = ((const unsigned*)ws)[WS_MAXK + (tid - 2 * DIM)];
        unsigned ub = (key & 0x80000000u) ? (key & 0x7fffffffu) : ~key;
        xs[tid] = __uint_as_float(ub);
    }
    __syncthreads();
    float p0 = (q == 0) ? bd[c] : 0.0f, p1 = 0.f;
#pragma unroll
    for (int kk = q * 48; kk < q * 48 + 48; kk += 2) {
        p0 += xs[kk] * Wd[kk * DIM + c];
        p1 += xs[kk + 1] * Wd[(kk + 1) * DIM + c];
    }
    hp[q][c] = p0 + p1;
    __syncthreads();
    if (tid < DIM) {
        float h = hp[0][tid] + hp[1][tid] + hp[2][tid] + hp[3][tid];
        float s = h;
#pragma unroll
        for (int off = 32; off >= 1; off >>= 1) s += __shfl_xor(s, off);
        float mu = s * (1.0f / DIM);
        float dif = h - mu;
        float s2 = dif * dif;
#pragma unroll
        for (int off = 32; off >= 1; off >>= 1) s2 += __shfl_xor(s2, off);
        float var = s2 * (1.0f / DIM);
        float rs = rsqrtf(var + 1e-5f);
        float o = dif * rs * lng[tid] + lnb[tid];
        out[i * DIM + tid] = fmaxf(o, 0.0f);
    }
}

// ---------------------------------------------------------------- launcher
extern "C" void kernel_launch(void* const* d_in, const int* in_sizes, int n_in,
                              void* d_out, int out_size, void* d_ws, size_t ws_size,
                              hipStream_t stream) {
    (void)in_sizes; (void)n_in; (void)out_size; (void)ws_size;
    const float* feat = (const float*)d_in[0];
    const float* dist = (const float*)d_in[1];
    const float* Wqkv = (const float*)d_in[2];
    const float* bqkv = (const float*)d_in[3];
    const float* Wg1  = (const float*)d_in[4];
    const float* bg1  = (const float*)d_in[5];
    const float* Wg2  = (const float*)d_in[6];
    const float* bg2  = (const float*)d_in[7];
    const float* tx   = (const float*)d_in[8];
    const float* ty   = (const float*)d_in[9];
    const float* tz   = (const float*)d_in[10];
    const float* Wd   = (const float*)d_in[11];
    const float* bd   = (const float*)d_in[12];
    const float* lng  = (const float*)d_in[13];
    const float* lnb  = (const float*)d_in[14];
    float* ws = (float*)d_ws;
    float* out = (float*)d_out;

    hipLaunchKernelGGL(k_qkv, dim3(N), dim3(192), 0, stream, feat, Wqkv, bqkv, Wg1, bg1, ws);
    hipLaunchKernelGGL(k_attn, dim3(N), dim3(256), 0, stream, dist, tx, ty, tz, Wg2, bg2, ws);
    hipLaunchKernelGGL(k_final, dim3(N), dim3(256), 0, stream, ws, Wd, bd, lng, lnb, out);
}

// Round 13
// 132.945 us; speedup vs baseline: 5.3047x; 1.1580x over previous
//
#include <hip/hip_runtime.h>
#include <hip/hip_bf16.h>
#include <math.h>

#define N 512
#define DIM 64

typedef __attribute__((ext_vector_type(8))) short short8;
typedef __attribute__((ext_vector_type(4))) float f32x4;

// workspace layout (units: floats from base)
#define WS_Q 0
#define WS_B (N*DIM)
#define WS_A (2*N*DIM)
#define WS_ATT (3*N*DIM)
#define WS_MEAN (4*N*DIM)
#define WS_MAXK (4*N*DIM + DIM)       // uint keys
#define WS_KV (4*N*DIM + 2*DIM)       // uint: (bf16(K)<<16)|bf16(V)

__device__ __forceinline__ unsigned short f2bf(float f) {
    unsigned u = __float_as_uint(f);
    return (unsigned short)((u + 0x7fffu + ((u >> 16) & 1u)) >> 16);
}

// ------------------------------------------------- qkv + A/B + KV-pack
__global__ void k_qkv(const float* __restrict__ feat, const float* __restrict__ Wqkv,
                      const float* __restrict__ bqkv, const float* __restrict__ Wg1,
                      const float* __restrict__ bg1, float* __restrict__ ws) {
    __shared__ float frow[DIM];
    __shared__ float qrow[DIM];
    __shared__ float krow[DIM];
    __shared__ float vrow[DIM];
    int i = blockIdx.x;
    int c = threadIdx.x;              // 0..191
    if (i == 0 && c < DIM) {
        ws[WS_MEAN + c] = 0.0f;
        ((unsigned*)ws)[WS_MAXK + c] = 0u;
    }
    if (c < DIM) frow[c] = feat[i * DIM + c];
    __syncthreads();
    float a0 = bqkv[c], a1 = 0.f, a2 = 0.f, a3 = 0.f;
#pragma unroll
    for (int kk = 0; kk < DIM; kk += 4) {
        a0 += frow[kk + 0] * Wqkv[(kk + 0) * 3 * DIM + c];
        a1 += frow[kk + 1] * Wqkv[(kk + 1) * 3 * DIM + c];
        a2 += frow[kk + 2] * Wqkv[(kk + 2) * 3 * DIM + c];
        a3 += frow[kk + 3] * Wqkv[(kk + 3) * 3 * DIM + c];
    }
    float acc = (a0 + a1) + (a2 + a3);
    if (c < DIM) {
        ws[WS_Q + i * DIM + c] = acc;
        qrow[c] = acc;
    } else if (c < 2 * DIM) {
        krow[c - DIM] = acc;
    } else {
        vrow[c - 2 * DIM] = acc;
    }
    __syncthreads();
    if (c < DIM) {
        float b0 = bg1[c], b1 = 0.f, b2 = 0.f, b3 = 0.f;
#pragma unroll
    for (int kk = 0; kk < DIM; kk += 4) {
            b0 += qrow[kk + 0] * Wg1[(kk + 0) * DIM + c];
            b1 += qrow[kk + 1] * Wg1[(kk + 1) * DIM + c];
            b2 += qrow[kk + 2] * Wg1[(kk + 2) * DIM + c];
            b3 += qrow[kk + 3] * Wg1[(kk + 3) * DIM + c];
        }
        ws[WS_A + i * DIM + c] = (b0 + b1) + (b2 + b3);
    } else if (c < 2 * DIM) {
        int cc = c - DIM;
        float b0 = 0.f, b1 = 0.f, b2 = 0.f, b3 = 0.f;
#pragma unroll
        for (int kk = 0; kk < DIM; kk += 4) {
            b0 += krow[kk + 0] * Wg1[(kk + 0) * DIM + cc];
            b1 += krow[kk + 1] * Wg1[(kk + 1) * DIM + cc];
            b2 += krow[kk + 2] * Wg1[(kk + 2) * DIM + cc];
            b3 += krow[kk + 3] * Wg1[(kk + 3) * DIM + cc];
        }
        ws[WS_B + i * DIM + cc] = (b0 + b1) + (b2 + b3);
    } else {
        int cc = c - 2 * DIM;
        ((unsigned*)ws)[WS_KV + i * DIM + cc] =
            ((unsigned)f2bf(krow[cc]) << 16) | (unsigned)f2bf(vrow[cc]);
    }
}

// ---------------------------------------------------------- fused attention
// one block per query row i; 8 waves x 512 threads; barrier-free main loop.
// Deferred-max softmax (rel2 bounded ~|15| << 127): l += exp2, a += exp2*v —
// no online-max chain, merges are plain sums. Tables packed per row as
// uint2{bf16(eq)|bf16(ek*LOG2E), f32(ev)} -> one ds_read_b64 per table.
// K/V packed bf16 in ws -> one global dword per element.
__global__ __launch_bounds__(512, 2) void k_attn(
    const float* __restrict__ dist,
    const float* __restrict__ tx, const float* __restrict__ ty,
    const float* __restrict__ tz, const float* __restrict__ Wg2,
    const float* __restrict__ bg2, float* __restrict__ ws) {
    __shared__ uint2 sxp[24 * 65];
    __shared__ uint2 syp[24 * 65];
    __shared__ uint2 szp[16 * 65];
    __shared__ int sidx[N];
    __shared__ float smrg[8][4][16][2];   // [wave][n][l15][{l,a}]

    const int i = blockIdx.x;
    const int tid = threadIdx.x;
    const int w = tid >> 6;          // 0..7
    const int lane = tid & 63;
    const int l15 = lane & 15;
    const int kg = lane >> 4;
    const float LOG2E = 1.4426950408889634f;

    for (int t = tid; t < 24 * 64; t += 512) {
        int row = t >> 6, d = t & 63, o = row * 65 + d;
        sxp[o] = make_uint2((__float_as_uint(tx[t]) & 0xffff0000u) |
                            (__float_as_uint(tx[1536 + t] * LOG2E) >> 16),
                            __float_as_uint(tx[3072 + t]));
        syp[o] = make_uint2((__float_as_uint(ty[t]) & 0xffff0000u) |
                            (__float_as_uint(ty[1536 + t] * LOG2E) >> 16),
                            __float_as_uint(ty[3072 + t]));
    }
    for (int t = tid; t < 16 * 64; t += 512) {
        int row = t >> 6, d = t & 63, o = row * 65 + d;
        szp[o] = make_uint2((__float_as_uint(tz[t]) & 0xffff0000u) |
                            (__float_as_uint(tz[1024 + t] * LOG2E) >> 16),
                            __float_as_uint(tz[2048 + t]));
    }
    for (int j = tid; j < N; j += 512) {
        const float* dp = dist + ((size_t)i * N + j) * 3;
        int ix = min((int)floorf((dp[0] + 3.0f) * 4.0f), 23);
        int iy = min((int)floorf((dp[1] + 3.0f) * 4.0f), 23);
        int iz = min((int)floorf((dp[2] + 2.0f) * 4.0f), 15);
        sidx[j] = ix | (iy << 5) | (iz << 10);
    }

    short8 wB[4][2];
#pragma unroll
    for (int n = 0; n < 4; ++n)
#pragma unroll
        for (int ks = 0; ks < 2; ++ks) {
            union { short8 v; unsigned short u[8]; } tmp;
#pragma unroll
            for (int e = 0; e < 8; ++e)
                tmp.u[e] = f2bf(Wg2[(ks * 32 + kg * 8 + e) * DIM + n * 16 + l15] * LOG2E);
            wB[n][ks] = tmp.v;
        }
    float af[2][8];
    {
        const float* ap = ws + WS_A + i * DIM + kg * 8;
#pragma unroll
        for (int ks = 0; ks < 2; ++ks)
#pragma unroll
            for (int e = 0; e < 8; ++e) af[ks][e] = ap[ks * 32 + e];
    }
    float qr[4], br[4];
#pragma unroll
    for (int n = 0; n < 4; ++n) {
        qr[n] = ws[WS_Q + i * DIM + n * 16 + l15] * LOG2E;
        br[n] = bg2[n * 16 + l15] * LOG2E;
    }

    const float* Bp = ws + WS_B;
    const unsigned* kvp = (const unsigned*)ws + WS_KV;

    float stl[4] = {0.f, 0.f, 0.f, 0.f};
    float sta[4] = {0.f, 0.f, 0.f, 0.f};
    __syncthreads();

    // 32 slices of 16 j; wave w takes slices w, w+8, w+16, w+24
#pragma unroll 2
    for (int t4 = 0; t4 < 4; ++t4) {
        const int j0w = (w + 8 * t4) * 16;
        short8 h[2];
        {
            const float* bb = Bp + (j0w + l15) * DIM + kg * 8;
#pragma unroll
            for (int ks = 0; ks < 2; ++ks) {
                union { short8 v; unsigned short u[8]; } hh;
#pragma unroll
                for (int e = 0; e < 8; ++e)
                    hh.u[e] = f2bf(fmaxf(af[ks][e] - bb[ks * 32 + e], 0.f));
                h[ks] = hh.v;
            }
        }
        f32x4 acc[4];
#pragma unroll
        for (int n = 0; n < 4; ++n) {
            acc[n] = (f32x4)(br[n]);   // fold bg2*LOG2E into C-init
            acc[n] = __builtin_amdgcn_mfma_f32_16x16x32_bf16(h[0], wB[n][0], acc[n], 0, 0, 0);
            acc[n] = __builtin_amdgcn_mfma_f32_16x16x32_bf16(h[1], wB[n][1], acc[n], 0, 0, 0);
        }
        int pk[4];
#pragma unroll
        for (int rr = 0; rr < 4; ++rr) pk[rr] = sidx[j0w + kg * 4 + rr];
#pragma unroll
        for (int n = 0; n < 4; ++n) {
            const int dof = n * 16 + l15;
#pragma unroll
            for (int rr = 0; rr < 4; ++rr) {
                int ix = pk[rr] & 31, iy = (pk[rr] >> 5) & 31, iz = pk[rr] >> 10;
                uint2 gx = sxp[ix * 65 + dof];
                uint2 gy = syp[iy * 65 + dof];
                uint2 gz = szp[iz * 65 + dof];
                float eq = __uint_as_float(gx.x & 0xffff0000u) +
                           __uint_as_float(gy.x & 0xffff0000u) +
                           __uint_as_float(gz.x & 0xffff0000u);
                float ek = __uint_as_float(gx.x << 16) +
                           __uint_as_float(gy.x << 16) +
                           __uint_as_float(gz.x << 16);      // LOG2E-scaled
                float ev = __uint_as_float(gx.y) + __uint_as_float(gy.y) +
                           __uint_as_float(gz.y);
                int j = j0w + kg * 4 + rr;
                unsigned ukv = kvp[j * DIM + dof];
                float kv = __uint_as_float(ukv & 0xffff0000u);
                float vv = __uint_as_float(ukv << 16);
                float rel2 = acc[n][rr] + qr[n] * eq + kv * ek;  // log2-domain
                float p = exp2f(rel2);
                stl[n] += p;
                sta[n] = fmaf(p, vv + ev, sta[n]);
            }
        }
    }

    // merge kg subgroups within wave (plain sums), then across 8 waves
#pragma unroll
    for (int n = 0; n < 4; ++n) {
#pragma unroll
        for (int off = 16; off <= 32; off <<= 1) {
            stl[n] += __shfl_xor(stl[n], off);
            sta[n] += __shfl_xor(sta[n], off);
        }
        if (lane < 16) {
            smrg[w][n][l15][0] = stl[n];
            smrg[w][n][l15][1] = sta[n];
        }
    }
    __syncthreads();
    if (tid < DIM) {
        int n = tid >> 4, c = tid & 15;
        float l = 0.f, a = 0.f;
#pragma unroll
        for (int ww = 0; ww < 8; ++ww) {
            l += smrg[ww][n][c][0];
            a += smrg[ww][n][c][1];
        }
        float att = a / l;
        ws[WS_ATT + i * DIM + tid] = att;
        atomicAdd(ws + WS_MEAN + tid, att);
        unsigned u = __float_as_uint(att);
        unsigned key = (u & 0x80000000u) ? ~u : (u | 0x80000000u);
        atomicMax((unsigned*)ws + WS_MAXK + tid, key);
    }
}

// ------------------------------------------- final GEMM + LayerNorm + ReLU
__global__ void k_final(const float* __restrict__ ws, const float* __restrict__ Wd,
                        const float* __restrict__ bd, const float* __restrict__ lng,
                        const float* __restrict__ lnb, float* __restrict__ out) {
    __shared__ float xs[3 * DIM];
    __shared__ float hp[4][DIM];
    int i = blockIdx.x;
    int tid = threadIdx.x;            // 0..255
    int c = tid & 63, q = tid >> 6;
    if (tid < DIM) xs[tid] = ws[WS_ATT + i * DIM + tid];
    else if (tid < 2 * DIM) xs[tid] = ws[WS_MEAN + (tid - DIM)] * (1.0f / (float)N);
    else if (tid < 3 * DIM) {
        unsigned key = ((const unsigned*)ws)[WS_MAXK + (tid - 2 * DIM)];
        unsigned ub = (key & 0x80000000u) ? (key & 0x7fffffffu) : ~key;
        xs[tid] = __uint_as_float(ub);
    }
    __syncthreads();
    float p0 = (q == 0) ? bd[c] : 0.0f, p1 = 0.f;
#pragma unroll
    for (int kk = q * 48; kk < q * 48 + 48; kk += 2) {
        p0 += xs[kk] * Wd[kk * DIM + c];
        p1 += xs[kk + 1] * Wd[(kk + 1) * DIM + c];
    }
    hp[q][c] = p0 + p1;
    __syncthreads();
    if (tid < DIM) {
        float h = hp[0][tid] + hp[1][tid] + hp[2][tid] + hp[3][tid];
        float s = h;
#pragma unroll
        for (int off = 32; off >= 1; off >>= 1) s += __shfl_xor(s, off);
        float mu = s * (1.0f / DIM);
        float dif = h - mu;
        float s2 = dif * dif;
#pragma unroll
        for (int off = 32; off >= 1; off >>= 1) s2 += __shfl_xor(s2, off);
        float var = s2 * (1.0f / DIM);
        float rs = rsqrtf(var + 1e-5f);
        float o = dif * rs * lng[tid] + lnb[tid];
        out[i * DIM + tid] = fmaxf(o, 0.0f);
    }
}

// ---------------------------------------------------------------- launcher
extern "C" void kernel_launch(void* const* d_in, const int* in_sizes, int n_in,
                              void* d_out, int out_size, void* d_ws, size_t ws_size,
                              hipStream_t stream) {
    (void)in_sizes; (void)n_in; (void)out_size; (void)ws_size;
    const float* feat = (const float*)d_in[0];
    const float* dist = (const float*)d_in[1];
    const float* Wqkv = (const float*)d_in[2];
    const float* bqkv = (const float*)d_in[3];
    const float* Wg1  = (const float*)d_in[4];
    const float* bg1  = (const float*)d_in[5];
    const float* Wg2  = (const float*)d_in[6];
    const float* bg2  = (const float*)d_in[7];
    const float* tx   = (const float*)d_in[8];
    const float* ty   = (const float*)d_in[9];
    const float* tz   = (const float*)d_in[10];
    const float* Wd   = (const float*)d_in[11];
    const float* bd   = (const float*)d_in[12];
    const float* lng  = (const float*)d_in[13];
    const float* lnb  = (const float*)d_in[14];
    float* ws = (float*)d_ws;
    float* out = (float*)d_out;

    hipLaunchKernelGGL(k_qkv, dim3(N), dim3(192), 0, stream, feat, Wqkv, bqkv, Wg1, bg1, ws);
    hipLaunchKernelGGL(k_attn, dim3(N), dim3(512), 0, stream, dist, tx, ty, tz, Wg2, bg2, ws);
    hipLaunchKernelGGL(k_final, dim3(N), dim3(256), 0, stream, ws, Wd, bd, lng, lnb, out);
}

// Round 14
// 130.876 us; speedup vs baseline: 5.3886x; 1.0158x over previous
//
#include <hip/hip_runtime.h>
#include <hip/hip_bf16.h>
#include <math.h>

#define N 512
#define DIM 64

typedef __attribute__((ext_vector_type(8))) short short8;
typedef __attribute__((ext_vector_type(4))) float f32x4;

// workspace layout (units: floats from base)
#define WS_Q 0
#define WS_B (N*DIM)
#define WS_A (2*N*DIM)
#define WS_ATT (3*N*DIM)
#define WS_MEAN (4*N*DIM)
#define WS_MAXK (4*N*DIM + DIM)       // uint keys
#define WS_KV (4*N*DIM + 2*DIM)       // uint: (bf16(K)<<16)|bf16(V)

__device__ __forceinline__ unsigned short f2bf(float f) {
    unsigned u = __float_as_uint(f);
    return (unsigned short)((u + 0x7fffu + ((u >> 16) & 1u)) >> 16);
}

// native 2^x — one v_exp_f32; exp2f w/o fast-math goes through OCML libcall
__device__ __forceinline__ float fexp2(float x) {
    float r;
    asm("v_exp_f32 %0, %1" : "=v"(r) : "v"(x));
    return r;
}

// ------------------------------------------------- qkv + A/B + KV-pack
__global__ void k_qkv(const float* __restrict__ feat, const float* __restrict__ Wqkv,
                      const float* __restrict__ bqkv, const float* __restrict__ Wg1,
                      const float* __restrict__ bg1, float* __restrict__ ws) {
    __shared__ float frow[DIM];
    __shared__ float qrow[DIM];
    __shared__ float krow[DIM];
    __shared__ float vrow[DIM];
    int i = blockIdx.x;
    int c = threadIdx.x;              // 0..191
    if (i == 0 && c < DIM) {
        ws[WS_MEAN + c] = 0.0f;
        ((unsigned*)ws)[WS_MAXK + c] = 0u;
    }
    if (c < DIM) frow[c] = feat[i * DIM + c];
    __syncthreads();
    float a0 = bqkv[c], a1 = 0.f, a2 = 0.f, a3 = 0.f;
#pragma unroll
    for (int kk = 0; kk < DIM; kk += 4) {
        a0 += frow[kk + 0] * Wqkv[(kk + 0) * 3 * DIM + c];
        a1 += frow[kk + 1] * Wqkv[(kk + 1) * 3 * DIM + c];
        a2 += frow[kk + 2] * Wqkv[(kk + 2) * 3 * DIM + c];
        a3 += frow[kk + 3] * Wqkv[(kk + 3) * 3 * DIM + c];
    }
    float acc = (a0 + a1) + (a2 + a3);
    if (c < DIM) {
        ws[WS_Q + i * DIM + c] = acc;
        qrow[c] = acc;
    } else if (c < 2 * DIM) {
        krow[c - DIM] = acc;
    } else {
        vrow[c - 2 * DIM] = acc;
    }
    __syncthreads();
    if (c < DIM) {
        float b0 = bg1[c], b1 = 0.f, b2 = 0.f, b3 = 0.f;
#pragma unroll
    for (int kk = 0; kk < DIM; kk += 4) {
            b0 += qrow[kk + 0] * Wg1[(kk + 0) * DIM + c];
            b1 += qrow[kk + 1] * Wg1[(kk + 1) * DIM + c];
            b2 += qrow[kk + 2] * Wg1[(kk + 2) * DIM + c];
            b3 += qrow[kk + 3] * Wg1[(kk + 3) * DIM + c];
        }
        ws[WS_A + i * DIM + c] = (b0 + b1) + (b2 + b3);
    } else if (c < 2 * DIM) {
        int cc = c - DIM;
        float b0 = 0.f, b1 = 0.f, b2 = 0.f, b3 = 0.f;
#pragma unroll
        for (int kk = 0; kk < DIM; kk += 4) {
            b0 += krow[kk + 0] * Wg1[(kk + 0) * DIM + cc];
            b1 += krow[kk + 1] * Wg1[(kk + 1) * DIM + cc];
            b2 += krow[kk + 2] * Wg1[(kk + 2) * DIM + cc];
            b3 += krow[kk + 3] * Wg1[(kk + 3) * DIM + cc];
        }
        ws[WS_B + i * DIM + cc] = (b0 + b1) + (b2 + b3);
    } else {
        int cc = c - 2 * DIM;
        ((unsigned*)ws)[WS_KV + i * DIM + cc] =
            ((unsigned)f2bf(krow[cc]) << 16) | (unsigned)f2bf(vrow[cc]);
    }
}

// ---------------------------------------------------------- fused attention
// one block per query row i; 8 waves x 512 threads; barrier-free main loop.
// Deferred-max softmax (rel2 bounded ~|15| << 127): l += exp2, a += exp2*v —
// no online-max chain, merges are plain sums. Tables packed per row as
// uint2{bf16(eq)|bf16(ek*LOG2E), f32(ev)} -> one ds_read_b64 per table.
// K/V packed bf16 in ws -> one global dword per element.
__global__ __launch_bounds__(512, 2) void k_attn(
    const float* __restrict__ dist,
    const float* __restrict__ tx, const float* __restrict__ ty,
    const float* __restrict__ tz, const float* __restrict__ Wg2,
    const float* __restrict__ bg2, float* __restrict__ ws) {
    __shared__ uint2 sxp[24 * 65];
    __shared__ uint2 syp[24 * 65];
    __shared__ uint2 szp[16 * 65];
    __shared__ int sidx[N];
    __shared__ float smrg[8][4][16][2];   // [wave][n][l15][{l,a}]

    const int i = blockIdx.x;
    const int tid = threadIdx.x;
    const int w = tid >> 6;          // 0..7
    const int lane = tid & 63;
    const int l15 = lane & 15;
    const int kg = lane >> 4;
    const float LOG2E = 1.4426950408889634f;

    for (int t = tid; t < 24 * 64; t += 512) {
        int row = t >> 6, d = t & 63, o = row * 65 + d;
        sxp[o] = make_uint2((__float_as_uint(tx[t]) & 0xffff0000u) |
                            (__float_as_uint(tx[1536 + t] * LOG2E) >> 16),
                            __float_as_uint(tx[3072 + t]));
        syp[o] = make_uint2((__float_as_uint(ty[t]) & 0xffff0000u) |
                            (__float_as_uint(ty[1536 + t] * LOG2E) >> 16),
                            __float_as_uint(ty[3072 + t]));
    }
    for (int t = tid; t < 16 * 64; t += 512) {
        int row = t >> 6, d = t & 63, o = row * 65 + d;
        szp[o] = make_uint2((__float_as_uint(tz[t]) & 0xffff0000u) |
                            (__float_as_uint(tz[1024 + t] * LOG2E) >> 16),
                            __float_as_uint(tz[2048 + t]));
    }
    for (int j = tid; j < N; j += 512) {
        const float* dp = dist + ((size_t)i * N + j) * 3;
        int ix = min((int)floorf((dp[0] + 3.0f) * 4.0f), 23);
        int iy = min((int)floorf((dp[1] + 3.0f) * 4.0f), 23);
        int iz = min((int)floorf((dp[2] + 2.0f) * 4.0f), 15);
        sidx[j] = ix | (iy << 5) | (iz << 10);
    }

    short8 wB[4][2];
#pragma unroll
    for (int n = 0; n < 4; ++n)
#pragma unroll
        for (int ks = 0; ks < 2; ++ks) {
            union { short8 v; unsigned short u[8]; } tmp;
#pragma unroll
            for (int e = 0; e < 8; ++e)
                tmp.u[e] = f2bf(Wg2[(ks * 32 + kg * 8 + e) * DIM + n * 16 + l15] * LOG2E);
            wB[n][ks] = tmp.v;
        }
    float af[2][8];
    {
        const float* ap = ws + WS_A + i * DIM + kg * 8;
#pragma unroll
        for (int ks = 0; ks < 2; ++ks)
#pragma unroll
            for (int e = 0; e < 8; ++e) af[ks][e] = ap[ks * 32 + e];
    }
    float qr[4], br[4];
#pragma unroll
    for (int n = 0; n < 4; ++n) {
        qr[n] = ws[WS_Q + i * DIM + n * 16 + l15] * LOG2E;
        br[n] = bg2[n * 16 + l15] * LOG2E;
    }

    const float* Bp = ws + WS_B;
    const unsigned* kvp = (const unsigned*)ws + WS_KV;

    float stl[4] = {0.f, 0.f, 0.f, 0.f};
    float sta[4] = {0.f, 0.f, 0.f, 0.f};
    __syncthreads();

    // 32 slices of 16 j; wave w takes slices w, w+8, w+16, w+24
#pragma unroll 2
    for (int t4 = 0; t4 < 4; ++t4) {
        const int j0w = (w + 8 * t4) * 16;
        short8 h[2];
        {
            const float* bb = Bp + (j0w + l15) * DIM + kg * 8;
#pragma unroll
            for (int ks = 0; ks < 2; ++ks) {
                union { short8 v; unsigned short u[8]; } hh;
#pragma unroll
                for (int e = 0; e < 8; ++e)
                    hh.u[e] = f2bf(fmaxf(af[ks][e] - bb[ks * 32 + e], 0.f));
                h[ks] = hh.v;
            }
        }
        f32x4 acc[4];
#pragma unroll
        for (int n = 0; n < 4; ++n) {
            acc[n] = (f32x4)(br[n]);   // fold bg2*LOG2E into C-init
            acc[n] = __builtin_amdgcn_mfma_f32_16x16x32_bf16(h[0], wB[n][0], acc[n], 0, 0, 0);
            acc[n] = __builtin_amdgcn_mfma_f32_16x16x32_bf16(h[1], wB[n][1], acc[n], 0, 0, 0);
        }
        int pk[4];
#pragma unroll
        for (int rr = 0; rr < 4; ++rr) pk[rr] = sidx[j0w + kg * 4 + rr];
#pragma unroll
        for (int n = 0; n < 4; ++n) {
            const int dof = n * 16 + l15;
#pragma unroll
            for (int rr = 0; rr < 4; ++rr) {
                int ix = pk[rr] & 31, iy = (pk[rr] >> 5) & 31, iz = pk[rr] >> 10;
                uint2 gx = sxp[ix * 65 + dof];
                uint2 gy = syp[iy * 65 + dof];
                uint2 gz = szp[iz * 65 + dof];
                float eq = __uint_as_float(gx.x & 0xffff0000u) +
                           __uint_as_float(gy.x & 0xffff0000u) +
                           __uint_as_float(gz.x & 0xffff0000u);
                float ek = __uint_as_float(gx.x << 16) +
                           __uint_as_float(gy.x << 16) +
                           __uint_as_float(gz.x << 16);      // LOG2E-scaled
                float ev = __uint_as_float(gx.y) + __uint_as_float(gy.y) +
                           __uint_as_float(gz.y);
                int j = j0w + kg * 4 + rr;
                unsigned ukv = kvp[j * DIM + dof];
                float kv = __uint_as_float(ukv & 0xffff0000u);
                float vv = __uint_as_float(ukv << 16);
                float rel2 = acc[n][rr] + qr[n] * eq + kv * ek;  // log2-domain
                float p = fexp2(rel2);
                stl[n] += p;
                sta[n] = fmaf(p, vv + ev, sta[n]);
            }
        }
    }

    // merge kg subgroups within wave (plain sums), then across 8 waves
#pragma unroll
    for (int n = 0; n < 4; ++n) {
#pragma unroll
        for (int off = 16; off <= 32; off <<= 1) {
            stl[n] += __shfl_xor(stl[n], off);
            sta[n] += __shfl_xor(sta[n], off);
        }
        if (lane < 16) {
            smrg[w][n][l15][0] = stl[n];
            smrg[w][n][l15][1] = sta[n];
        }
    }
    __syncthreads();
    if (tid < DIM) {
        int n = tid >> 4, c = tid & 15;
        float l = 0.f, a = 0.f;
#pragma unroll
        for (int ww = 0; ww < 8; ++ww) {
            l += smrg[ww][n][c][0];
            a += smrg[ww][n][c][1];
        }
        float att = a / l;
        ws[WS_ATT + i * DIM + tid] = att;
        atomicAdd(ws + WS_MEAN + tid, att);
        unsigned u = __float_as_uint(att);
        unsigned key = (u & 0x80000000u) ? ~u : (u | 0x80000000u);
        atomicMax((unsigned*)ws + WS_MAXK + tid, key);
    }
}

// ------------------------------------------- final GEMM + LayerNorm + ReLU
__global__ void k_final(const float* __restrict__ ws, const float* __restrict__ Wd,
                        const float* __restrict__ bd, const float* __restrict__ lng,
                        const float* __restrict__ lnb, float* __restrict__ out) {
    __shared__ float xs[3 * DIM];
    __shared__ float hp[4][DIM];
    int i = blockIdx.x;
    int tid = threadIdx.x;            // 0..255
    int c = tid & 63, q = tid >> 6;
    if (tid < DIM) xs[tid] = ws[WS_ATT + i * DIM + tid];
    else if (tid < 2 * DIM) xs[tid] = ws[WS_MEAN + (tid - DIM)] * (1.0f / (float)N);
    else if (tid < 3 * DIM) {
        unsigned key = ((const unsigned*)ws)[WS_MAXK + (tid - 2 * DIM)];
        unsigned ub = (key & 0x80000000u) ? (key & 0x7fffffffu) : ~key;
        xs[tid] = __uint_as_float(ub);
    }
    __syncthreads();
    float p0 = (q == 0) ? bd[c] : 0.0f, p1 = 0.f;
#pragma unroll
    for (int kk = q * 48; kk < q * 48 + 48; kk += 2) {
        p0 += xs[kk] * Wd[kk * DIM + c];
        p1 += xs[kk + 1] * Wd[(kk + 1) * DIM + c];
    }
    hp[q][c] = p0 + p1;
    __syncthreads();
    if (tid < DIM) {
        float h = hp[0][tid] + hp[1][tid] + hp[2][tid] + hp[3][tid];
        float s = h;
#pragma unroll
        for (int off = 32; off >= 1; off >>= 1) s += __shfl_xor(s, off);
        float mu = s * (1.0f / DIM);
        float dif = h - mu;
        float s2 = dif * dif;
#pragma unroll
        for (int off = 32; off >= 1; off >>= 1) s2 += __shfl_xor(s2, off);
        float var = s2 * (1.0f / DIM);
        float rs = rsqrtf(var + 1e-5f);
        float o = dif * rs * lng[tid] + lnb[tid];
        out[i * DIM + tid] = fmaxf(o, 0.0f);
    }
}

// ---------------------------------------------------------------- launcher
extern "C" void kernel_launch(void* const* d_in, const int* in_sizes, int n_in,
                              void* d_out, int out_size, void* d_ws, size_t ws_size,
                              hipStream_t stream) {
    (void)in_sizes; (void)n_in; (void)out_size; (void)ws_size;
    const float* feat = (const float*)d_in[0];
    const float* dist = (const float*)d_in[1];
    const float* Wqkv = (const float*)d_in[2];
    const float* bqkv = (const float*)d_in[3];
    const float* Wg1  = (const float*)d_in[4];
    const float* bg1  = (const float*)d_in[5];
    const float* Wg2  = (const float*)d_in[6];
    const float* bg2  = (const float*)d_in[7];
    const float* tx   = (const float*)d_in[8];
    const float* ty   = (const float*)d_in[9];
    const float* tz   = (const float*)d_in[10];
    const float* Wd   = (const float*)d_in[11];
    const float* bd   = (const float*)d_in[12];
    const float* lng  = (const float*)d_in[13];
    const float* lnb  = (const float*)d_in[14];
    float* ws = (float*)d_ws;
    float* out = (float*)d_out;

    hipLaunchKernelGGL(k_qkv, dim3(N), dim3(192), 0, stream, feat, Wqkv, bqkv, Wg1, bg1, ws);
    hipLaunchKernelGGL(k_attn, dim3(N), dim3(512), 0, stream, dist, tx, ty, tz, Wg2, bg2, ws);
    hipLaunchKernelGGL(k_final, dim3(N), dim3(256), 0, stream, ws, Wd, bd, lng, lnb, out);
}